// Round 13
// baseline (60.519 us; speedup 1.0000x reference)
//
#include <hip/hip_runtime.h>
#include <math.h>

// Problem constants (fixed by setup_inputs)
#define U_TOTAL 40000
#define N_PTS   32
#define C_IN    9
#define C_OUT   64
#define NPOINTS (U_TOTAL * N_PTS)          // 1,280,000 points
#define TILE_PTS    256                    // points per tile (= 8 u)
#define TILE_FLOATS (TILE_PTS * C_IN)      // 2304 floats = 9216 B
#define NTILES  (NPOINTS / TILE_PTS)       // 5000 (exact)
#define GRID_A  1024                       // heavy-pass grid (4 blocks/CU)
#define NSUM    54                         // 9 first + 45 tri second moments
#define EPSV    1e-3f

typedef float    f32x2  __attribute__((ext_vector_type(2)));
typedef float    f32x16 __attribute__((ext_vector_type(16)));
typedef short    short8 __attribute__((ext_vector_type(8)));
typedef unsigned u32x4  __attribute__((ext_vector_type(4)));

__device__ __forceinline__ unsigned pk_bf16(float lo, float hi) {
    unsigned r;
    asm("v_cvt_pk_bf16_f32 %0, %1, %2" : "=v"(r) : "v"(lo), "v"(hi));
    return r;
}

// Triangular moment index for (i,j), i<=j, compile-time under full unroll.
#define TRI_IDX(i, j) (C_IN + 9 * (i) - ((i) * ((i) - 1)) / 2 + ((j) - (i)))

// ---------------------------------------------------------------------------
// Pass A (fused max + moments): ONE full 46 MB sweep (round-12 lesson: each
// full sweep costs ~13-15 us regardless of structure -- so make only one).
// 1024 persistent blocks x 256 thr (4 blocks/CU, launch_bounds(256,4)).
// Per 256-point tile (coalesced float4 -> LDS transpose, next tile's regs
// prefetched before compute):
//  - MFMA path (verified since R3, absmax 0.03125): wave w handles u=2w,2w+1;
//    bf16 A-frag from 5 LDS floats (g=lane>>5 holds k{4g..4g+3}+k8(g=0),
//    k>=9 zero), 2x mfma_32x32x16_bf16 vs RAW W fragments, packed-max D
//    reduction -> raw per-u channel max straight to out. BN affine + relu
//    commute with the max (scale>0), applied later by pfn_c.
//  - Moment path: thread's point (9 floats, 9*tid mod 32 bank permutation)
//    -> acc[54] via constant-trip 9x9 nest (VGPR-resident; R10 lesson).
// Epilogue: 3-level shfl fold, park 32 rows in LDS, column-sum, transposed
// partials[54][1024] store (no atomics, no memset -- R11 lesson).
// ---------------------------------------------------------------------------
__global__ __launch_bounds__(256, 4)
void pfn_a(const float* __restrict__ in, const float* __restrict__ Wg,
           float* __restrict__ out, float* __restrict__ partials)
{
    __shared__ float lbuf[TILE_FLOATS];
    const int tid  = threadIdx.x;
    const int lane = tid & 63;
    const int w    = tid >> 6;
    const int col  = lane & 31;
    const int g    = lane >> 5;

    // ---- RAW W bf16 fragments (register resident; verified K-layout)
    {
    }
    const float* wr0 = Wg + (size_t)col * C_IN + g * 4;
    const float* wr1 = Wg + (size_t)(32 + col) * C_IN + g * 4;
    u32x4 b0, b1;
    b0[0] = pk_bf16(wr0[0], wr0[1]);
    b0[1] = pk_bf16(wr0[2], wr0[3]);
    b0[2] = pk_bf16(g ? 0.f : Wg[(size_t)col * C_IN + 8], 0.f);
    b0[3] = 0u;
    b1[0] = pk_bf16(wr1[0], wr1[1]);
    b1[1] = pk_bf16(wr1[2], wr1[3]);
    b1[2] = pk_bf16(g ? 0.f : Wg[(size_t)(32 + col) * C_IN + 8], 0.f);
    b1[3] = 0u;
    const short8 B0v = __builtin_bit_cast(short8, b0);
    const short8 B1v = __builtin_bit_cast(short8, b1);

    float acc[NSUM];
#pragma unroll
    for (int v = 0; v < NSUM; ++v) acc[v] = 0.f;

    int tile = blockIdx.x;
    const float4* src = (const float4*)(in + (size_t)tile * TILE_FLOATS);
    float4 v0 = src[tid], v1 = src[tid + 256], v2 = {};
    if (tid < 64) v2 = src[tid + 512];

    while (tile < NTILES) {
        __syncthreads();                       // prev readers done
        ((float4*)lbuf)[tid]       = v0;
        ((float4*)lbuf)[tid + 256] = v1;
        if (tid < 64) ((float4*)lbuf)[tid + 512] = v2;
        __syncthreads();

        const int nt = tile + GRID_A;
        if (nt < NTILES) {                     // prefetch next tile's regs
            const float4* ns = (const float4*)(in + (size_t)nt * TILE_FLOATS);
            v0 = ns[tid]; v1 = ns[tid + 256];
            if (tid < 64) v2 = ns[tid + 512];
        }

        // ---- moments for this thread's point
        {
            float pv[C_IN];
            const float* p = lbuf + tid * C_IN;
#pragma unroll
            for (int k = 0; k < C_IN; ++k) pv[k] = p[k];
#pragma unroll
            for (int k = 0; k < C_IN; ++k) acc[k] += pv[k];
#pragma unroll
            for (int i = 0; i < C_IN; ++i)
#pragma unroll
                for (int j = 0; j < C_IN; ++j)
                    if (j >= i)                // compile-time guard
                        acc[TRI_IDX(i, j)] = fmaf(pv[i], pv[j], acc[TRI_IDX(i, j)]);
        }

        // ---- MFMA raw max for this wave's 2 u
#pragma unroll
        for (int t = 0; t < 2; ++t) {
            const int uloc = 2 * w + t;
            const float* p = lbuf + (size_t)(uloc * N_PTS + col) * C_IN;
            u32x4 a;
            a[0] = pk_bf16(p[4 * g], p[4 * g + 1]);
            a[1] = pk_bf16(p[4 * g + 2], p[4 * g + 3]);
            a[2] = pk_bf16(g ? 0.f : p[8], 0.f);
            a[3] = 0u;
            const short8 Av = __builtin_bit_cast(short8, a);
            const f32x16 z = {};
            float m0, m1;
            {
                f32x16 d = __builtin_amdgcn_mfma_f32_32x32x16_bf16(Av, B0v, z, 0, 0, 0);
                f32x2 mx = {d[0], d[1]};
#pragma unroll
                for (int i = 1; i < 8; ++i) {
                    f32x2 q = {d[2 * i], d[2 * i + 1]};
                    mx = __builtin_elementwise_max(mx, q);
                }
                m0 = fmaxf(mx.x, mx.y);
                m0 = fmaxf(m0, __shfl_xor(m0, 32));   // fold other 16 rows
            }
            {
                f32x16 d = __builtin_amdgcn_mfma_f32_32x32x16_bf16(Av, B1v, z, 0, 0, 0);
                f32x2 mx = {d[0], d[1]};
#pragma unroll
                for (int i = 1; i < 8; ++i) {
                    f32x2 q = {d[2 * i], d[2 * i + 1]};
                    mx = __builtin_elementwise_max(mx, q);
                }
                m1 = fmaxf(mx.x, mx.y);
                m1 = fmaxf(m1, __shfl_xor(m1, 32));
            }
            // lane -> channel lane (g ? 32+col : col); raw max, no BN yet
            out[(size_t)(tile * 8 + uloc) * C_OUT + lane] = g ? m1 : m0;
        }
        tile = nt;
    }

    // ---- fold 8 consecutive lanes, park 32 rows in LDS, column-sum, store
#pragma unroll
    for (int v = 0; v < NSUM; ++v) {
        acc[v] += __shfl_xor(acc[v], 1);
        acc[v] += __shfl_xor(acc[v], 2);
        acc[v] += __shfl_xor(acc[v], 4);
    }
    __syncthreads();                           // lbuf reuse
    if ((tid & 7) == 0) {
        float* row = lbuf + (tid >> 3) * NSUM;
#pragma unroll
        for (int v = 0; v < NSUM; ++v) row[v] = acc[v];
    }
    __syncthreads();
    if (tid < NSUM) {
        float s = 0.f;
#pragma unroll
        for (int r = 0; r < 32; ++r) s += lbuf[r * NSUM + tid];
        partials[(size_t)tid * GRID_A + blockIdx.x] = s;   // [54][1024]
    }
}

// ---------------------------------------------------------------------------
// Prep: ONE block. Fold partials[54][1024] -> moments (221 KB, coalesced
// rows, ~1 us), then threads 0..63 build per-channel scale/shift:
// mean_o = (w_o . Sp)/M, E2_o = (w_o^T S w_o)/M, var biased; scale =
// gamma*rsqrt(var+eps), shift = beta - mean*scale. consts = [scale64|shift64].
// ---------------------------------------------------------------------------
__global__ __launch_bounds__(256)
void pfn_prep(const float* __restrict__ partials, const float* __restrict__ Wg,
              const float* __restrict__ gamma, const float* __restrict__ beta,
              float* __restrict__ consts)
{
    __shared__ float sums[NSUM];
    const int t = threadIdx.x;

#pragma unroll
    for (int m = 0; m < NSUM; ++m) {
        const float* row = partials + (size_t)m * GRID_A;
        float a = row[t] + row[t + 256] + row[t + 512] + row[t + 768];
#pragma unroll
        for (int s = 1; s <= 32; s <<= 1) a += __shfl_xor(a, s);
        __syncthreads();
        if (t == 0)   sums[m] = a;             // wave-0 lane-0 total
        else if (t == 64 || t == 128 || t == 192) {
            // other waves' totals folded via LDS atomics-free: park + add
        }
        __syncthreads();
        if (t < 64 && t > 0) {}                // no-op (keep uniform)
        // fold the 4 wave-totals: lanes 0 of each wave hold a
        if ((t & 63) == 0 && t > 0) atomicAdd(&sums[m], a);  // LDS atomic, 3 adds
        __syncthreads();
    }

    if (t < C_OUT) {
        float wv[C_IN];
#pragma unroll
        for (int k = 0; k < C_IN; ++k) wv[k] = Wg[(size_t)t * C_IN + k];
        float sp = 0.f;
#pragma unroll
        for (int k = 0; k < C_IN; ++k) sp = fmaf(wv[k], sums[k], sp);
        float e2 = 0.f;
#pragma unroll
        for (int i = 0; i < C_IN; ++i)
#pragma unroll
            for (int j = 0; j < C_IN; ++j)
                if (j >= i) {
                    const float f = (i == j) ? 1.f : 2.f;
                    e2 = fmaf(f * wv[i] * wv[j], sums[TRI_IDX(i, j)], e2);
                }
        const float invM = 1.f / (float)NPOINTS;
        const float mean = sp * invM;
        const float var  = fmaf(-mean, mean, e2 * invM);
        const float sc   = gamma[t] * __frsqrt_rn(var + EPSV);
        consts[t]         = sc;
        consts[C_OUT + t] = beta[t] - mean * sc;
    }
}

// ---------------------------------------------------------------------------
// Pass C: in-place y = relu(scale*x + shift) on out, float4. 20.5 MB.
// ---------------------------------------------------------------------------
__global__ __launch_bounds__(256)
void pfn_c(float* __restrict__ out, const float* __restrict__ consts)
{
    const int idx = blockIdx.x * 256 + threadIdx.x;   // float4 index
    const int o4  = idx & 15;                         // channel-quad
    float4 x  = ((const float4*)out)[idx];
    float4 sc = ((const float4*)consts)[o4];
    float4 sh = ((const float4*)consts)[16 + o4];
    x.x = fmaxf(fmaf(x.x, sc.x, sh.x), 0.f);
    x.y = fmaxf(fmaf(x.y, sc.y, sh.y), 0.f);
    x.z = fmaxf(fmaf(x.z, sc.z, sh.z), 0.f);
    x.w = fmaxf(fmaf(x.w, sc.w, sh.w), 0.f);
    ((float4*)out)[idx] = x;
}

extern "C" void kernel_launch(void* const* d_in, const int* in_sizes, int n_in,
                              void* d_out, int out_size, void* d_ws, size_t ws_size,
                              hipStream_t stream)
{
    const float* in    = (const float*)d_in[0];
    const float* Wg    = (const float*)d_in[1];
    const float* gamma = (const float*)d_in[2];
    const float* beta  = (const float*)d_in[3];
    float* out = (float*)d_out;

    float* partials = (float*)d_ws;                     // 54 x 1024 floats
    float* consts   = partials + (size_t)NSUM * GRID_A; // 128 floats

    pfn_a   <<<GRID_A, 256, 0, stream>>>(in, Wg, out, partials);
    pfn_prep<<<1,      256, 0, stream>>>(partials, Wg, gamma, beta, consts);
    pfn_c   <<<(U_TOTAL * C_OUT / 4) / 256, 256, 0, stream>>>(out, consts);
}